// Round 12
// baseline (150.789 us; speedup 1.0000x reference)
//
#include <hip/hip_runtime.h>

// ---- problem constants (fixed by reference setup_inputs) ----
constexpr int B_  = 32;
constexpr int Na  = 512;
constexpr int Nv  = 256;
constexpr int D   = 384;

constexpr int NK2 = D / 64;    // 6 k-chunks of 64 (one scaled MFMA each)

// fp8 operand regions, one 32-row group x 384 k = 12 KB per group.
// A-side (a8): unit kc (1 KB): byte = h2*512 + r*16 + j holding
//   value[row r][k = kc*32 + h2*16 + j]; MFMA lane l reads 16 B at l*16.
//   K=64 operand = unit 2q2 (regs0-3) + unit 2q2+1 (regs4-7).
// V-side (b8): k64-unit q2 (2 KB): lane l's 32 B contiguous at l*32 ->
//   ONE int8v global deref (2 coalesced dwordx4).
// The (lane,byte)->k packing is IDENTICAL for A-slot and B-slot operands,
// so the contraction is exact under operand swap; scales = 1.0 (e8m0 0x7F)
// make the scaled MFMA numerically identical to non-scaled fp8.
constexpr int AGROUPS = B_ * 16;   // 512 groups (bi*16+rg), rows linear
constexpr int BGROUPS = B_ * 8;    // 256 groups (bj*8+cg), rows linear
constexpr size_t GROUP_BYTES = 12 * 1024;
constexpr int SCALE_ONE = 0x7F7F7F7F;   // e8m0 127 = 2^0 in every byte

typedef int   int4v    __attribute__((ext_vector_type(4)));
typedef int   int8v    __attribute__((ext_vector_type(8)));
typedef float floatx16 __attribute__((ext_vector_type(16)));

// 16B-per-lane async global->LDS (lane i writes LDS slot base + i*16)
__device__ __forceinline__ void async_load16(const void* g, void* l) {
    __builtin_amdgcn_global_load_lds(
        (const __attribute__((address_space(1))) unsigned int*)g,
        (__attribute__((address_space(3))) unsigned int*)l,
        16, 0, 0);
}

// ---- K1: zero output + fp32 -> fp8(e4m3 OCP) conversion (3x k-split grid) ----
__global__ void convert_fp8_kernel(const float* __restrict__ a, const float* __restrict__ v,
                                   unsigned char* __restrict__ a8,
                                   unsigned char* __restrict__ b8,
                                   float* __restrict__ out) {
    int gid = blockIdx.x * blockDim.x + threadIdx.x;
    if (gid < B_ * B_) out[gid] = 0.0f;    // d_out is poisoned before every launch

    const int blk = blockIdx.x / 3;        // group 0..767
    const int p   = blockIdx.x % 3;        // k-third 0..2
    const bool isA = blk < AGROUPS;
    const float* src;
    unsigned char* dst;
    if (isA) {                                 // A rows are linear: group*32 + r
        src = a + (size_t)blk * 32 * D;
        dst = a8 + (size_t)blk * GROUP_BYTES;
    } else {
        int b2 = blk - AGROUPS;
        src = v + (size_t)b2 * 32 * D;
        dst = b8 + (size_t)b2 * GROUP_BYTES;
    }
    const int t = threadIdx.x;
    const int r = t >> 3, q = t & 7;

    int k0 = p * 128 + q * 16;
    const float4* s4 = (const float4*)(src + (size_t)r * D + k0);
    float4 f0 = s4[0], f1 = s4[1], f2 = s4[2], f3 = s4[3];
    int w0 = 0, w1 = 0, w2 = 0, w3 = 0;
    w0 = __builtin_amdgcn_cvt_pk_fp8_f32(f0.x, f0.y, w0, false);
    w0 = __builtin_amdgcn_cvt_pk_fp8_f32(f0.z, f0.w, w0, true);
    w1 = __builtin_amdgcn_cvt_pk_fp8_f32(f1.x, f1.y, w1, false);
    w1 = __builtin_amdgcn_cvt_pk_fp8_f32(f1.z, f1.w, w1, true);
    w2 = __builtin_amdgcn_cvt_pk_fp8_f32(f2.x, f2.y, w2, false);
    w2 = __builtin_amdgcn_cvt_pk_fp8_f32(f2.z, f2.w, w2, true);
    w3 = __builtin_amdgcn_cvt_pk_fp8_f32(f3.x, f3.y, w3, false);
    w3 = __builtin_amdgcn_cvt_pk_fp8_f32(f3.z, f3.w, w3, true);
    int kc = k0 >> 5;
    int h2 = (k0 >> 4) & 1;
    size_t off;
    if (isA) {
        off = (size_t)kc * 1024 + h2 * 512 + r * 16;            // A layout
    } else {
        int q2 = kc >> 1, u = kc & 1, l = r + 32 * h2;          // lane-32B units
        off = (size_t)q2 * 2048 + l * 32 + u * 16;
    }
    int4v o = { w0, w1, w2, w3 };
    *(int4v*)(dst + off) = o;
}

// sum of exp2(a[i] * 1/(tau*ln2)) over one accumulator, pairwise tree.
// RAW v_exp_f32: |x| <= ~60, inside the exact range of the HW instruction.
__device__ __forceinline__ float expsum16(floatx16 a) {
    constexpr float INV_TAU_LN2 = 0.7213475204444817f;  // 1/(tau*ln2), tau=2
    float e[16];
    #pragma unroll
    for (int i = 0; i < 16; ++i)
        e[i] = __builtin_amdgcn_exp2f(a[i] * INV_TAU_LN2);
    float t0 = (e[0] + e[1])  + (e[2] + e[3]);
    float t1 = (e[4] + e[5])  + (e[6] + e[7]);
    float t2 = (e[8] + e[9])  + (e[10] + e[11]);
    float t3 = (e[12] + e[13]) + (e[14] + e[15]);
    return (t0 + t1) + (t2 + t3);
}

// ---- K2: fused MX-scaled fp8 GEMM + lse-pool. STAGE-ONCE 8-TILE SWEEP. ----
// R11 post-mortem: ports NOT saturated (LDS 70%, VMEM 47% at full MFMA rate);
// the wall is 8 sequential rounds/CU of 2 LOCKSTEP blocks, each serializing
// stage (~2.4k cy) -> k-loop -> quarter-rate-TRANS epilogue (~1k cy/wave):
// 2 x 8 x (sum) ~= the measured 128k cy wall. Fix: 512 persistent-ish blocks
// (2/CU); each stages its 48 KB A ONCE and sweeps 8 bj-tiles (V is direct-
// global, so tile switch is free). Per-tile lse partials go to ms[8] LDS
// WITHOUT syncthreads; ONE barrier + merge at the end. The 48-chunk MFMA
// stream has no barriers and no re-staging: stage traffic /8 (196->24.6 MB),
// epilogue TRANS sits between chunk streams where the other (drifted) block's
// MFMAs cover it, next-tile V latency hides under the epilogue.
__global__ __launch_bounds__(256, 2) void gemm_lse_kernel(
        const unsigned char* __restrict__ a8,
        const unsigned char* __restrict__ b8,
        float* __restrict__ out)
{
    __shared__ unsigned char ldsA[48 * 1024];   // block's 4 A-groups, whole K
    __shared__ float ms[8][4][4][32];           // [tile][v-quarter][a-group][row]

    const int tid  = threadIdx.x;
    const int lane = tid & 63;
    const int wn   = tid >> 6;       // 4 waves = 4 v-quarters (64 v each)

    // decode: 512 blocks = 8 xcd x 4 bi_lo x 4 rb x 4 bjq. bi tied to XCD =>
    // per-XCD L2 set = A(4 bi) 768KB + V(all) 3.1MB ~= 3.9MB <= 4MB.
    int b = blockIdx.x;
    const int xcd   = b & 7;      b >>= 3;
    const int bi_lo = b & 3;      b >>= 2;
    const int rb    = b & 3;      b >>= 2;   // row-block: 128 audio rows
    const int bjq   = b;                      // bj quad: tiles bj = bjq*8 .. +7
    const int bi    = xcd * 4 + bi_lo;        // 0..31

    // ---- stage A once: 48 KB (groups bi*16+rb*4 .. +3); wave wn stages group wn ----
    {
        const unsigned char* gsrc = a8 + (size_t)(bi * 16 + rb * 4 + wn) * GROUP_BYTES
                                       + (size_t)lane * 16;
        unsigned char* ldst = ldsA + (size_t)wn * GROUP_BYTES;
        #pragma unroll
        for (int kc = 0; kc < 12; ++kc)
            async_load16(gsrc + (size_t)kc * 1024, ldst + kc * 1024);
    }
    __syncthreads();   // the ONLY barrier before the final merge

    const unsigned char* la = ldsA + (size_t)lane * 16;
    // tile 0 V base for this wave's 2 v-groups
    const unsigned char* pv0 = b8 + (size_t)((bjq * 8) * 8 + wn * 2) * GROUP_BYTES
                                  + (size_t)lane * 32;

    int8v Vc0 = *(const int8v*)pv0;
    int8v Vc1 = *(const int8v*)(pv0 + GROUP_BYTES);

    for (int ti = 0; ti < 8; ++ti) {
        floatx16 acc[4][2];   // [audio group][v group]
        #pragma unroll
        for (int g = 0; g < 4; ++g)
            #pragma unroll
            for (int vg = 0; vg < 2; ++vg)
                acc[g][vg] = (floatx16)(0.0f);

        #pragma unroll
        for (int q2 = 0; q2 < NK2; ++q2) {
            // distance-1 V prefetch: next chunk, or next TILE's chunk 0
            // (bj+1 => base advances 8*GROUP_BYTES). No barrier ever drains it.
            const bool pre = (q2 < NK2 - 1) || (ti < 7);
            int8v Vn0, Vn1;
            if (pre) {
                const unsigned char* np = (q2 < NK2 - 1)
                    ? pv0 + (size_t)(q2 + 1) * 2048
                    : pv0 + (size_t)8 * GROUP_BYTES;
                Vn0 = *(const int8v*)np;
                Vn1 = *(const int8v*)(np + GROUP_BYTES);
            }
            // A: 4 groups' k64 operands from LDS (8 lane-contiguous ds_read_b128)
            int8v A[4];
            #pragma unroll
            for (int g = 0; g < 4; ++g) {
                const unsigned char* p = la + (size_t)g * GROUP_BYTES + (size_t)q2 * 2048;
                int4v lo = *(const int4v*)p;
                int4v hi = *(const int4v*)(p + 1024);
                A[g] = __builtin_shufflevector(lo, hi, 0, 1, 2, 3, 4, 5, 6, 7);
            }
            // 8 MFMAs, 8 independent acc chains; V regs reused 4x, A regs 2x
            __builtin_amdgcn_s_setprio(1);
            #pragma unroll
            for (int g = 0; g < 4; ++g) {
                acc[g][0] = __builtin_amdgcn_mfma_scale_f32_32x32x64_f8f6f4(
                    Vc0, A[g], acc[g][0], 0, 0, 0, SCALE_ONE, 0, SCALE_ONE);
                acc[g][1] = __builtin_amdgcn_mfma_scale_f32_32x32x64_f8f6f4(
                    Vc1, A[g], acc[g][1], 0, 0, 0, SCALE_ONE, 0, SCALE_ONE);
            }
            __builtin_amdgcn_s_setprio(0);
            if (pre) { Vc0 = Vn0; Vc1 = Vn1; }
        }
        pv0 += (size_t)8 * GROUP_BYTES;   // advance to next tile's base

        // per-tile epilogue: per-thread exp-sum over this wave's 64 v.
        // C/D layout (shape-determined): audio row = lane&31 within a-group;
        // regs & lane>>5 = v indices. (no max: |sims/tau| <= ~55 -> exact)
        // Runs between chunk streams; next tile's V chunk 0 is in flight and
        // the co-resident (drifted) block's MFMAs cover the TRANS time.
        #pragma unroll
        for (int g = 0; g < 4; ++g) {
            float s = expsum16(acc[g][0]) + expsum16(acc[g][1]);
            s += __shfl_xor(s, 32);      // merge lane>>5 v-halves
            if (lane < 32) ms[ti][wn][g][lane] = s;
        }
        // NO __syncthreads here: merge deferred to the end.
    }

    __syncthreads();   // all waves' ms writes visible

    // final merge: wave wn handles tiles 2wn and 2wn+1; per tile, 2 passes of
    // 64 rows: merge 4 v-quarters (exp-space, exact), lse, wave-reduce, 1 atomic.
    #pragma unroll
    for (int p2 = 0; p2 < 2; ++p2) {
        const int ti = wn * 2 + p2;
        float acc_lse = 0.0f;
        #pragma unroll
        for (int pass = 0; pass < 2; ++pass) {
            const int row = pass * 64 + lane;
            const int g = row >> 5, r = row & 31;
            float e = (ms[ti][0][g][r] + ms[ti][1][g][r])
                    + (ms[ti][2][g][r] + ms[ti][3][g][r]);
            constexpr float TAU_LN2 = 1.3862943611198906f;  // tau*ln2 (v_log = log2)
            float lse = TAU_LN2 * __builtin_amdgcn_logf(e);
            #pragma unroll
            for (int m = 1; m < 64; m <<= 1) lse += __shfl_xor(lse, m);
            acc_lse += lse;
        }
        if (lane == 0)
            atomicAdd(&out[bi * 32 + bjq * 8 + ti], acc_lse * (1.0f / Na));
    }
}

extern "C" void kernel_launch(void* const* d_in, const int* in_sizes, int n_in,
                              void* d_out, int out_size, void* d_ws, size_t ws_size,
                              hipStream_t stream) {
    const float* audio  = (const float*)d_in[0];
    const float* visual = (const float*)d_in[1];
    float* out = (float*)d_out;

    unsigned char* a8 = (unsigned char*)d_ws;                        // 6.29 MB fp8 A
    unsigned char* b8 = a8 + (size_t)AGROUPS * GROUP_BYTES;          // +3.15 MB fp8 B

    convert_fp8_kernel<<<dim3((AGROUPS + BGROUPS) * 3), dim3(256), 0, stream>>>(
        audio, visual, a8, b8, out);
    // grid: 512 blocks x 4 waves, 2 blocks/CU; each block = 128 audio rows x
    // 8 bj tiles (A staged once, swept across bj)
    gemm_lse_kernel<<<dim3(512), dim3(256), 0, stream>>>(a8, b8, out);
}

// Round 13
// 126.099 us; speedup vs baseline: 1.1958x; 1.1958x over previous
//
#include <hip/hip_runtime.h>

// ---- problem constants (fixed by reference setup_inputs) ----
constexpr int B_  = 32;
constexpr int Na  = 512;
constexpr int Nv  = 256;
constexpr int D   = 384;

constexpr int NK2 = D / 64;    // 6 k-chunks of 64 (one scaled MFMA each)

// fp8 operand regions, one 32-row group x 384 k = 12 KB per group.
// A-side (a8): unit kc (1 KB): byte = h2*512 + r*16 + j holding
//   value[row r][k = kc*32 + h2*16 + j]; MFMA lane l reads 16 B at l*16.
//   K=64 operand = unit 2q2 (regs0-3) + unit 2q2+1 (regs4-7).
// V-side (b8): k64-unit q2 (2 KB): lane l's 32 B contiguous at l*32 ->
//   two dwordx4 at +0/+16, no register shuffling beyond one concat.
// The (lane,byte)->k packing is IDENTICAL for A-slot and B-slot operands,
// so the contraction is exact under operand swap; scales = 1.0 (e8m0 0x7F)
// make the scaled MFMA numerically identical to non-scaled fp8.
constexpr int AGROUPS = B_ * 16;   // 512 groups (bi*16+rg), rows linear
constexpr int BGROUPS = B_ * 8;    // 256 groups (bj*8+cg), rows linear
constexpr size_t GROUP_BYTES = 12 * 1024;
constexpr int SCALE_ONE = 0x7F7F7F7F;   // e8m0 127 = 2^0 in every byte

typedef int   int4v    __attribute__((ext_vector_type(4)));
typedef int   int8v    __attribute__((ext_vector_type(8)));
typedef float floatx16 __attribute__((ext_vector_type(16)));

// 16B-per-lane async global->LDS (lane i writes LDS slot base + i*16)
__device__ __forceinline__ void async_load16(const void* g, void* l) {
    __builtin_amdgcn_global_load_lds(
        (const __attribute__((address_space(1))) unsigned int*)g,
        (__attribute__((address_space(3))) unsigned int*)l,
        16, 0, 0);
}

// asm-volatile global load: UNSINKABLE by the scheduler (the mechanism that
// defeated every C++-level "prefetch" in R2-R11 — allocator sinks plain loads
// to their use, R3's VGPR=104 proved it). Completion is NOT tracked by the
// compiler: consumers must sit after an explicit counted s_waitcnt +
// sched_barrier(0) fence (rule #18).
#define VLOAD16(dst, ptr) \
    asm volatile("global_load_dwordx4 %0, %1, off" : "=v"(dst) : "v"(ptr))

// ---- K1: zero output + fp32 -> fp8(e4m3 OCP) conversion (3x k-split grid) ----
__global__ void convert_fp8_kernel(const float* __restrict__ a, const float* __restrict__ v,
                                   unsigned char* __restrict__ a8,
                                   unsigned char* __restrict__ b8,
                                   float* __restrict__ out) {
    int gid = blockIdx.x * blockDim.x + threadIdx.x;
    if (gid < B_ * B_) out[gid] = 0.0f;    // d_out is poisoned before every launch

    const int blk = blockIdx.x / 3;        // group 0..767
    const int p   = blockIdx.x % 3;        // k-third 0..2
    const bool isA = blk < AGROUPS;
    const float* src;
    unsigned char* dst;
    if (isA) {                                 // A rows are linear: group*32 + r
        src = a + (size_t)blk * 32 * D;
        dst = a8 + (size_t)blk * GROUP_BYTES;
    } else {
        int b2 = blk - AGROUPS;
        src = v + (size_t)b2 * 32 * D;
        dst = b8 + (size_t)b2 * GROUP_BYTES;
    }
    const int t = threadIdx.x;
    const int r = t >> 3, q = t & 7;

    int k0 = p * 128 + q * 16;
    const float4* s4 = (const float4*)(src + (size_t)r * D + k0);
    float4 f0 = s4[0], f1 = s4[1], f2 = s4[2], f3 = s4[3];
    int w0 = 0, w1 = 0, w2 = 0, w3 = 0;
    w0 = __builtin_amdgcn_cvt_pk_fp8_f32(f0.x, f0.y, w0, false);
    w0 = __builtin_amdgcn_cvt_pk_fp8_f32(f0.z, f0.w, w0, true);
    w1 = __builtin_amdgcn_cvt_pk_fp8_f32(f1.x, f1.y, w1, false);
    w1 = __builtin_amdgcn_cvt_pk_fp8_f32(f1.z, f1.w, w1, true);
    w2 = __builtin_amdgcn_cvt_pk_fp8_f32(f2.x, f2.y, w2, false);
    w2 = __builtin_amdgcn_cvt_pk_fp8_f32(f2.z, f2.w, w2, true);
    w3 = __builtin_amdgcn_cvt_pk_fp8_f32(f3.x, f3.y, w3, false);
    w3 = __builtin_amdgcn_cvt_pk_fp8_f32(f3.z, f3.w, w3, true);
    int kc = k0 >> 5;
    int h2 = (k0 >> 4) & 1;
    size_t off;
    if (isA) {
        off = (size_t)kc * 1024 + h2 * 512 + r * 16;            // A layout
    } else {
        int q2 = kc >> 1, u = kc & 1, l = r + 32 * h2;          // lane-32B units
        off = (size_t)q2 * 2048 + l * 32 + u * 16;
    }
    int4v o = { w0, w1, w2, w3 };
    *(int4v*)(dst + off) = o;
}

// sum of exp2(a[i] * 1/(tau*ln2)) over one accumulator, pairwise tree.
// RAW v_exp_f32: |x| <= ~60, inside the exact range of the HW instruction.
__device__ __forceinline__ float expsum16(floatx16 a) {
    constexpr float INV_TAU_LN2 = 0.7213475204444817f;  // 1/(tau*ln2), tau=2
    float e[16];
    #pragma unroll
    for (int i = 0; i < 16; ++i)
        e[i] = __builtin_amdgcn_exp2f(a[i] * INV_TAU_LN2);
    float t0 = (e[0] + e[1])  + (e[2] + e[3]);
    float t1 = (e[4] + e[5])  + (e[6] + e[7]);
    float t2 = (e[8] + e[9])  + (e[10] + e[11]);
    float t3 = (e[12] + e[13]) + (e[14] + e[15]);
    return (t0 + t1) + (t2 + t3);
}

// ---- K2: fused MX-scaled fp8 GEMM + lse-pool. ASM-PIPELINED V (distance 2). ----
// R11 arithmetic: MfmaUtil 39% @ 2 waves/SIMD => gap G ~2270 cy between MFMA
// clusters = V global-load latency taken at distance 0 (compiler sinks C++
// "prefetch" loads to use — R3 proved it; R9/R10's DMA alternative re-
// serialized through LDS+drains). Fix: V loads via asm volatile (unsinkable),
// 3-slot rotating register pipeline at DISTANCE 2 (~5600 cy coverage), counted
// vmcnt(8) waits + sched_barrier(0) fence before the consuming shuffles/MFMAs.
// A stays in LDS (staged once, ~150 cy reads, compiler-counted lgkmcnt).
// Regs: Vb 48 + A 32 + misc ~30 arch + acc 128 AGPR ~= 238 < 256 (no spill).
__global__ __launch_bounds__(256, 2) void gemm_lse_kernel(
        const unsigned char* __restrict__ a8,
        const unsigned char* __restrict__ b8,
        float* __restrict__ out)
{
    __shared__ unsigned char ldsA[48 * 1024];   // block's 4 A-groups, whole K
    __shared__ float ms[4][4][32];              // [v-quarter][a-group][row]

    const int tid  = threadIdx.x;
    const int lane = tid & 63;
    const int wn   = tid >> 6;       // 4 waves = 4 v-quarters (64 v each)

    // XCD-chunked decode: bi tied to blockIdx%8 => per-XCD L2 set =
    // A(4 bi) 786KB + V(all) 3.1MB ~= 3.9MB <= 4MB.
    int b = blockIdx.x;
    const int xcd   = b & 7;      b >>= 3;
    const int bi_lo = b & 3;      b >>= 2;
    const int rb    = b & 3;      b >>= 2;   // row-block: 128 audio rows
    const int bj    = b;                      // 0..31
    const int bi    = xcd * 4 + bi_lo;        // 0..31

    // ---- stage A once: 48 KB (groups bi*16+rb*4 .. +3); wave wn stages group wn ----
    {
        const unsigned char* gsrc = a8 + (size_t)(bi * 16 + rb * 4 + wn) * GROUP_BYTES
                                       + (size_t)lane * 16;
        unsigned char* ldst = ldsA + (size_t)wn * GROUP_BYTES;
        #pragma unroll
        for (int kc = 0; kc < 12; ++kc)
            async_load16(gsrc + (size_t)kc * 1024, ldst + kc * 1024);
    }

    const unsigned char* pv0 = b8 + (size_t)(bj * 8 + wn * 2) * GROUP_BYTES
                                  + (size_t)lane * 32;
    const unsigned char* pv1 = pv0 + GROUP_BYTES;

    // ---- V register pipeline: slots 0..2, chunk c -> slot c%3, 4 loads/chunk.
    // Prologue: issue chunks 0 and 1 BEFORE __syncthreads (the sync drains
    // vmcnt(0), so both are resident when the loop starts; in-loop waits still
    // use the steady-state count).
    int4v Vb[3][2][2];   // [slot][v-group][16B half] — all indices constant
    VLOAD16(Vb[0][0][0], pv0);
    VLOAD16(Vb[0][0][1], pv0 + 16);
    VLOAD16(Vb[0][1][0], pv1);
    VLOAD16(Vb[0][1][1], pv1 + 16);
    VLOAD16(Vb[1][0][0], pv0 + 2048);
    VLOAD16(Vb[1][0][1], pv0 + 2048 + 16);
    VLOAD16(Vb[1][1][0], pv1 + 2048);
    VLOAD16(Vb[1][1][1], pv1 + 2048 + 16);

    __syncthreads();   // A visible to all waves (also drains V chunks 0,1 — OK)

    const unsigned char* la = ldsA + (size_t)lane * 16;

    floatx16 acc[4][2];   // [audio group][v group]
    #pragma unroll
    for (int g = 0; g < 4; ++g)
        #pragma unroll
        for (int vg = 0; vg < 2; ++vg)
            acc[g][vg] = (floatx16)(0.0f);

    #pragma unroll
    for (int q2 = 0; q2 < NK2; ++q2) {
        // A: 4 groups' k64 operands from LDS (8 lane-contiguous ds_read_b128;
        // compiler emits counted lgkmcnt before first use — below the fence)
        int8v A[4];
        #pragma unroll
        for (int g = 0; g < 4; ++g) {
            const unsigned char* p = la + (size_t)g * GROUP_BYTES + (size_t)q2 * 2048;
            int4v lo = *(const int4v*)p;
            int4v hi = *(const int4v*)(p + 1024);
            A[g] = __builtin_shufflevector(lo, hi, 0, 1, 2, 3, 4, 5, 6, 7);
        }
        // issue chunk q2+2's V loads into the slot freed at iter q2-1
        if (q2 + 2 < NK2) {
            const int s = (q2 + 2) % 3;
            const unsigned char* np0 = pv0 + (size_t)(q2 + 2) * 2048;
            const unsigned char* np1 = pv1 + (size_t)(q2 + 2) * 2048;
            VLOAD16(Vb[s][0][0], np0);
            VLOAD16(Vb[s][0][1], np0 + 16);
            VLOAD16(Vb[s][1][0], np1);
            VLOAD16(Vb[s][1][1], np1 + 16);
        }
        // counted wait: everything except the newest 8 loads (chunks q2+1,q2+2)
        // is complete => chunk q2 resident. Never 0 mid-loop.
        if (q2 + 2 < NK2)      { asm volatile("s_waitcnt vmcnt(8)"); }
        else if (q2 + 1 < NK2) { asm volatile("s_waitcnt vmcnt(4)"); }
        else                   { asm volatile("s_waitcnt vmcnt(0)"); }
        __builtin_amdgcn_sched_barrier(0);   // fence: consumers stay BELOW

        const int cs = q2 % 3;
        int8v V0 = __builtin_shufflevector(Vb[cs][0][0], Vb[cs][0][1],
                                           0, 1, 2, 3, 4, 5, 6, 7);
        int8v V1 = __builtin_shufflevector(Vb[cs][1][0], Vb[cs][1][1],
                                           0, 1, 2, 3, 4, 5, 6, 7);

        // 8 MFMAs, 8 independent acc chains; V regs reused 4x, A regs 2x
        __builtin_amdgcn_s_setprio(1);
        #pragma unroll
        for (int g = 0; g < 4; ++g) {
            acc[g][0] = __builtin_amdgcn_mfma_scale_f32_32x32x64_f8f6f4(
                V0, A[g], acc[g][0], 0, 0, 0, SCALE_ONE, 0, SCALE_ONE);
            acc[g][1] = __builtin_amdgcn_mfma_scale_f32_32x32x64_f8f6f4(
                V1, A[g], acc[g][1], 0, 0, 0, SCALE_ONE, 0, SCALE_ONE);
        }
        __builtin_amdgcn_s_setprio(0);
    }

    // ---- epilogue: per-thread exp-sum over this wave's 64 v ----
    // C/D layout (shape-determined): audio row = lane&31 within a-group;
    // regs & lane>>5 = v indices. (no max: |sims/tau| <= ~55 -> exact)
    float s[4];
    #pragma unroll
    for (int g = 0; g < 4; ++g) {
        s[g] = expsum16(acc[g][0]) + expsum16(acc[g][1]);
        s[g] += __shfl_xor(s[g], 32);   // merge lane>>5 v-halves
    }
    if (lane < 32) {
        #pragma unroll
        for (int g = 0; g < 4; ++g)
            ms[wn][g][lane] = s[g];
    }
    __syncthreads();

    // merge the 4 v-quarters (exp-space, linear -> exact), then lse + mean.
    // 128 block rows handled by 2 waves; one atomic per reducer wave.
    if (tid < 128) {
        const int g = tid >> 5, r = tid & 31;
        float e = (ms[0][g][r] + ms[1][g][r]) + (ms[2][g][r] + ms[3][g][r]);
        constexpr float TAU_LN2 = 1.3862943611198906f;  // tau*ln2 (v_log = log2)
        float lse = TAU_LN2 * __builtin_amdgcn_logf(e);
        #pragma unroll
        for (int m = 1; m < 64; m <<= 1) lse += __shfl_xor(lse, m);
        if ((tid & 63) == 0)
            atomicAdd(&out[bi * 32 + bj], lse * (1.0f / Na));  // 4rb x 2 = 8 adds
    }
}

extern "C" void kernel_launch(void* const* d_in, const int* in_sizes, int n_in,
                              void* d_out, int out_size, void* d_ws, size_t ws_size,
                              hipStream_t stream) {
    const float* audio  = (const float*)d_in[0];
    const float* visual = (const float*)d_in[1];
    float* out = (float*)d_out;

    unsigned char* a8 = (unsigned char*)d_ws;                        // 6.29 MB fp8 A
    unsigned char* b8 = a8 + (size_t)AGROUPS * GROUP_BYTES;          // +3.15 MB fp8 B

    convert_fp8_kernel<<<dim3((AGROUPS + BGROUPS) * 3), dim3(256), 0, stream>>>(
        audio, visual, a8, b8, out);
    // grid: 4096 blocks x 4 waves = 16384 waves
    //     = 32 bi x 32 bj x 4 row-blocks, block = 128 audio rows x 256 v
    gemm_lse_kernel<<<dim3(4096), dim3(256), 0, stream>>>(a8, b8, out);
}